// Round 1
// baseline (215.220 us; speedup 1.0000x reference)
//
#include <hip/hip_runtime.h>

#define DEVI __device__ __forceinline__

typedef __attribute__((ext_vector_type(8))) short bh8;   // 8 x bf16 (4 VGPRs) MFMA A/B frag
typedef __attribute__((ext_vector_type(4))) float fx4;   // MFMA C/D frag

DEVI unsigned short f2b(float f){            // fp32 -> bf16, round-to-nearest-even
  unsigned u = __float_as_uint(f);
  u += 0x7FFFu + ((u >> 16) & 1u);
  return (unsigned short)(u >> 16);
}
DEVI float b2f(unsigned short b){ return __uint_as_float(((unsigned)b) << 16); }

typedef __attribute__((address_space(1))) const void gvoid;
typedef __attribute__((address_space(3))) void svoid;
DEVI void gload16(const void* g, void* l){
  // async global->LDS, 16B/lane; LDS dest = wave-uniform base + lane*16
  __builtin_amdgcn_global_load_lds((gvoid*)g, (svoid*)l, 16, 0, 0);
}

// ---------------------------------------------------------------- casts
__global__ __launch_bounds__(256) void cast_kernel(const float* __restrict__ in,
                                                   unsigned short* __restrict__ out, int n4){
  int i = blockIdx.x * 256 + threadIdx.x;
  if (i >= n4) return;
  float4 v = ((const float4*)in)[i];
  short4 r;
  r.x = (short)f2b(v.x); r.y = (short)f2b(v.y);
  r.z = (short)f2b(v.z); r.w = (short)f2b(v.w);
  ((short4*)out)[i] = r;
}

// ------------------------------------------------- bf16 GEMM: C = A * B^T
// A: MxK bf16 row-major, B: NxK bf16 row-major (i.e. B^T input), C: MxN
// MODE 0: write bf16. MODE 1: write fp32 + bias[col].
template<int MODE>
__global__ __launch_bounds__(256) void gemm_bt(
    const unsigned short* __restrict__ A, const unsigned short* __restrict__ B,
    unsigned short* __restrict__ Cb, float* __restrict__ Cf,
    const float* __restrict__ bias, int M, int N, int K)
{
  __shared__ short As[4096];  // [128][32] bf16
  __shared__ short Bs[4096];
  const int t = threadIdx.x, wv = t >> 6, ln = t & 63, lr = ln & 15, lg = ln >> 4;
  const int bm = blockIdx.y << 7, bn = blockIdx.x << 7;
  const int wr = wv >> 1, wc = wv & 1;   // 2x2 waves over 128x128, each 64x64
  const fx4 fz = {0.f, 0.f, 0.f, 0.f};
  fx4 acc[4][4];
#pragma unroll
  for (int i = 0; i < 4; i++)
#pragma unroll
    for (int j = 0; j < 4; j++) acc[i][j] = fz;

  for (int k0 = 0; k0 < K; k0 += 32){
#pragma unroll
    for (int i = 0; i < 2; i++){
      int c = i * 256 + t;              // chunk id, 8 bf16 each
      int row = c >> 2, col = (c & 3) << 3;
      gload16(A + (size_t)(bm + row) * K + k0 + col, As + (i << 11) + (wv << 9));
      gload16(B + (size_t)(bn + row) * K + k0 + col, Bs + (i << 11) + (wv << 9));
    }
    __syncthreads();
    bh8 af[4], bf[4];
#pragma unroll
    for (int mi = 0; mi < 4; mi++) af[mi] = *(const bh8*)&As[(wr*64 + mi*16 + lr)*32 + lg*8];
#pragma unroll
    for (int ni = 0; ni < 4; ni++) bf[ni] = *(const bh8*)&Bs[(wc*64 + ni*16 + lr)*32 + lg*8];
#pragma unroll
    for (int mi = 0; mi < 4; mi++)
#pragma unroll
      for (int ni = 0; ni < 4; ni++)
        acc[mi][ni] = __builtin_amdgcn_mfma_f32_16x16x32_bf16(af[mi], bf[ni], acc[mi][ni], 0, 0, 0);
    __syncthreads();
  }
  // D layout: col = lane&15, row = (lane>>4)*4 + r  [m89-verified]
#pragma unroll
  for (int mi = 0; mi < 4; mi++)
#pragma unroll
    for (int ni = 0; ni < 4; ni++){
      int col = bn + wc*64 + ni*16 + lr;
#pragma unroll
      for (int r = 0; r < 4; r++){
        int row = bm + wr*64 + mi*16 + lg*4 + r;
        float v = acc[mi][ni][r];
        if constexpr (MODE == 1) Cf[(size_t)row * N + col] = v + bias[col];
        else                     Cb[(size_t)row * N + col] = (short)f2b(v);
      }
    }
}

// ---------------------------- LayerNorm(q,k over HD=64) + RoPE + v-transpose
// in : qkv bf16 (B*N, 3072), col = which*1024 + h*64 + d
// out: q,k bf16 (B,H,N,64); vt bf16 (B,H,64,N)
__global__ __launch_bounds__(256) void lnrope_kernel(
    const unsigned short* __restrict__ qkv,
    const float* __restrict__ qw, const float* __restrict__ qb,
    const float* __restrict__ kw, const float* __restrict__ kb,
    unsigned short* __restrict__ qo, unsigned short* __restrict__ ko,
    unsigned short* __restrict__ vt)
{
  __shared__ short vl[64][66];          // [d][n_local], stride 66 -> conflict-free
  const int t = threadIdx.x, wv = t >> 6, ln = t & 63;
  const int nc = blockIdx.x & 31, h = (blockIdx.x >> 5) & 15, b = blockIdx.x >> 9;
  const int j = ln & 31;
  // inv_freq = 10000^(-j/32) ; ln(10000)/32 = 0.287823136624...
  const float freq = __expf(-(float)j * 0.28782313662425576f);
  const float gwq = qw[ln], gbq = qb[ln], gwk = kw[ln], gbk = kb[ln];
  const float sgn = (ln < 32) ? -1.0f : 1.0f;
  const size_t obase0 = ((size_t)(b*16 + h)) * 2048 * 64;
#pragma unroll 1
  for (int it = 0; it < 16; ++it){
    int nl = wv*16 + it;
    int n  = nc*64 + nl;
    size_t base = ((size_t)(b*2048 + n)) * 3072 + h*64 + ln;
    float qv = b2f(qkv[base]);
    float kv = b2f(qkv[base + 1024]);
    float vv = b2f(qkv[base + 2048]);
    float s1 = qv, s2 = qv*qv, s3 = kv, s4 = kv*kv;
#pragma unroll
    for (int off = 32; off; off >>= 1){
      s1 += __shfl_xor(s1, off); s2 += __shfl_xor(s2, off);
      s3 += __shfl_xor(s3, off); s4 += __shfl_xor(s4, off);
    }
    float mq = s1 * (1.f/64.f), mk = s3 * (1.f/64.f);
    float rq = rsqrtf(s2*(1.f/64.f) - mq*mq + 1e-5f);
    float rk = rsqrtf(s4*(1.f/64.f) - mk*mk + 1e-5f);
    float qn = (qv - mq) * rq * gwq + gbq;
    float kn = (kv - mk) * rk * gwk + gbk;
    int pos = n & 1023;                 // positions restart at n/2
    float ang = (float)pos * freq;
    float sv, cv; sincosf(ang, &sv, &cv);
    float qp = __shfl_xor(qn, 32);      // rotate-half partner
    float kp = __shfl_xor(kn, 32);
    size_t ob = obase0 + (size_t)n*64 + ln;
    qo[ob] = f2b(qn*cv + sgn*qp*sv);
    ko[ob] = f2b(kn*cv + sgn*kp*sv);
    vl[ln][nl] = (short)f2b(vv);
  }
  __syncthreads();
  int d = t >> 2, seg = t & 3;
  size_t vb = (((size_t)(b*16 + h))*64 + d) * 2048 + nc*64 + seg*16;
#pragma unroll
  for (int u = 0; u < 4; ++u){
    short4 pk;
    pk.x = vl[d][seg*16 + u*4 + 0]; pk.y = vl[d][seg*16 + u*4 + 1];
    pk.z = vl[d][seg*16 + u*4 + 2]; pk.w = vl[d][seg*16 + u*4 + 3];
    *(short4*)&vt[vb + u*4] = pk;
  }
}

// ------------------------------------------------------------ flash attention
// q,k: (B,H,N,64) bf16 ; vt: (B,H,64,N) bf16 ; o: (B,N,H*64) bf16
// grid: (B*H)*(N/64); 4 waves x 16 q-rows; KVBLK=64; XOR-swizzled LDS tiles.
__global__ __launch_bounds__(256) void attn_kernel(
    const unsigned short* __restrict__ qg, const unsigned short* __restrict__ kg,
    const unsigned short* __restrict__ vg, unsigned short* __restrict__ og)
{
  __shared__ short Ks[4096];   // [64 key][64 hd], 16B-slot XOR swizzle by row&7
  __shared__ short Vs[4096];   // [64 hd][64 key], same swizzle
  __shared__ short Ps[4096];   // per-wave [16 q][64 key], same swizzle
  const int t = threadIdx.x, wv = t >> 6, ln = t & 63, lr = ln & 15, lg = ln >> 4;
  const int qt = blockIdx.x & 31, bh = blockIdx.x >> 5;
  const int q0 = qt << 6;
  const unsigned short* kbase = kg + ((size_t)bh << 17);   // 2048*64
  const unsigned short* vbase = vg + ((size_t)bh << 17);
  const size_t qrow = ((size_t)bh << 11) + q0 + wv*16 + lr;
  bh8 qf0 = *(const bh8*)&qg[qrow*64 + lg*8];
  bh8 qf1 = *(const bh8*)&qg[qrow*64 + 32 + lg*8];
  const fx4 fz = {0.f,0.f,0.f,0.f};
  fx4 oacc[4]; float m_r[4], l_r[4];
#pragma unroll
  for (int i = 0; i < 4; i++){ oacc[i] = fz; m_r[i] = -1e30f; l_r[i] = 0.f; }
  const bool qfirst = (q0 < 1024);
  char* KsB = (char*)Ks; char* VsB = (char*)Vs;
  char* PsB = (char*)Ps + (wv << 11);

  for (int kt = 0; kt < 2048; kt += 64){
    // ---- stage K tile and V^T tile (pre-swizzled global source, linear LDS dest)
#pragma unroll
    for (int i = 0; i < 2; i++){
      int c = i*256 + t;
      int row = c >> 3, sl = (c & 7) ^ (row & 7);
      gload16(kbase + (size_t)(kt + row)*64 + sl*8, Ks + (i << 11) + (wv << 9));
      gload16(vbase + (size_t)row*2048 + kt + sl*8, Vs + (i << 11) + (wv << 9));
    }
    __syncthreads();
    // ---- S = Q K^T (16q x 64key per wave)
    fx4 sc[4];
#pragma unroll
    for (int nt = 0; nt < 4; nt++){
      sc[nt] = fz;
      int krow = nt*16 + lr, sw = krow & 7;
      bh8 kf0 = *(const bh8*)(KsB + krow*128 + ((lg ^ sw) << 4));
      bh8 kf1 = *(const bh8*)(KsB + krow*128 + (((4|lg) ^ sw) << 4));
      sc[nt] = __builtin_amdgcn_mfma_f32_16x16x32_bf16(qf0, kf0, sc[nt], 0, 0, 0);
      sc[nt] = __builtin_amdgcn_mfma_f32_16x16x32_bf16(qf1, kf1, sc[nt], 0, 0, 0);
    }
    // block-uniform bias: cross(input<->cond) tiles get log(0.5)
    const float bias = (qfirst != (kt < 1024)) ? -0.69314718056f : 0.0f;
    // ---- online softmax (fp32), rows = lg*4+r, cols = nt*16+lr
#pragma unroll
    for (int r = 0; r < 4; r++){
      float s0 = sc[0][r]*0.125f + bias, s1 = sc[1][r]*0.125f + bias;
      float s2 = sc[2][r]*0.125f + bias, s3 = sc[3][r]*0.125f + bias;
      float mx = fmaxf(fmaxf(s0, s1), fmaxf(s2, s3));
#pragma unroll
      for (int off = 1; off < 16; off <<= 1) mx = fmaxf(mx, __shfl_xor(mx, off));
      float mnew = fmaxf(m_r[r], mx);
      float corr = __expf(m_r[r] - mnew);
      m_r[r] = mnew;
      float p0 = __expf(s0 - mnew), p1 = __expf(s1 - mnew);
      float p2 = __expf(s2 - mnew), p3 = __expf(s3 - mnew);
      float sum = (p0 + p1) + (p2 + p3);
#pragma unroll
      for (int off = 1; off < 16; off <<= 1) sum += __shfl_xor(sum, off);
      l_r[r] = l_r[r]*corr + sum;
#pragma unroll
      for (int ht = 0; ht < 4; ht++) oacc[ht][r] *= corr;
      // P -> per-wave LDS (swizzled), row = qr, col = key
      int qr = lg*4 + r, swp = qr & 7;
      char* pb = PsB + qr*128;
      int hi = lr >> 3, lo = (lr & 7) << 1;
      *(short*)(pb + (((0 + hi) ^ swp) << 4) + lo) = (short)f2b(p0);
      *(short*)(pb + (((2 + hi) ^ swp) << 4) + lo) = (short)f2b(p1);
      *(short*)(pb + (((4 + hi) ^ swp) << 4) + lo) = (short)f2b(p2);
      *(short*)(pb + (((6 + hi) ^ swp) << 4) + lo) = (short)f2b(p3);
    }
    // ---- O += P V  (P as A-frag from LDS, V^T as B-frag)
    bh8 pf0 = *(const bh8*)(PsB + lr*128 + ((lg ^ (lr & 7)) << 4));
    bh8 pf1 = *(const bh8*)(PsB + lr*128 + (((4|lg) ^ (lr & 7)) << 4));
#pragma unroll
    for (int ht = 0; ht < 4; ht++){
      int vrow = ht*16 + lr, sv = vrow & 7;
      bh8 vf0 = *(const bh8*)(VsB + vrow*128 + ((lg ^ sv) << 4));
      bh8 vf1 = *(const bh8*)(VsB + vrow*128 + (((4|lg) ^ sv) << 4));
      oacc[ht] = __builtin_amdgcn_mfma_f32_16x16x32_bf16(pf0, vf0, oacc[ht], 0, 0, 0);
      oacc[ht] = __builtin_amdgcn_mfma_f32_16x16x32_bf16(pf1, vf1, oacc[ht], 0, 0, 0);
    }
    __syncthreads();
  }
  const int b = bh >> 4, h = bh & 15;
#pragma unroll
  for (int ht = 0; ht < 4; ht++)
#pragma unroll
    for (int r = 0; r < 4; r++){
      size_t row = (size_t)b*2048 + q0 + wv*16 + lg*4 + r;
      og[row*1024 + h*64 + ht*16 + lr] = f2b(oacc[ht][r] / l_r[r]);
    }
}

// ---------------------------------------------------------------- launcher
extern "C" void kernel_launch(void* const* d_in, const int* in_sizes, int n_in,
                              void* d_out, int out_size, void* d_ws, size_t ws_size,
                              hipStream_t stream)
{
  const float* x      = (const float*)d_in[0];
  const float* qkv_w  = (const float*)d_in[1];
  const float* qn_w   = (const float*)d_in[2];
  const float* qn_b   = (const float*)d_in[3];
  const float* kn_w   = (const float*)d_in[4];
  const float* kn_b   = (const float*)d_in[5];
  const float* proj_w = (const float*)d_in[6];
  const float* proj_b = (const float*)d_in[7];
  float* out = (float*)d_out;

  // workspace layout (bf16 elements); total 67.1 MB
  unsigned short* x16   = (unsigned short*)d_ws;          // 4096*1024
  unsigned short* w1    = x16   + (size_t)4096*1024;      // 3072*1024
  unsigned short* w2    = w1    + (size_t)3072*1024;      // 1024*1024
  unsigned short* qkv16 = w2    + (size_t)1024*1024;      // 4096*3072
  unsigned short* q16   = qkv16 + (size_t)4096*3072;      // 2*16*2048*64
  unsigned short* k16   = q16   + (size_t)4194304;
  unsigned short* vt16  = k16   + (size_t)4194304;
  unsigned short* o16   = qkv16;                          // alias: qkv dead after lnrope

  cast_kernel<<<4096, 256, 0, stream>>>(x,      x16, 1048576);
  cast_kernel<<<3072, 256, 0, stream>>>(qkv_w,  w1,   786432);
  cast_kernel<<<1024, 256, 0, stream>>>(proj_w, w2,   262144);
  gemm_bt<0><<<dim3(24, 32), 256, 0, stream>>>(x16, w1, qkv16, nullptr, nullptr, 4096, 3072, 1024);
  lnrope_kernel<<<1024, 256, 0, stream>>>(qkv16, qn_w, qn_b, kn_w, kn_b, q16, k16, vt16);
  attn_kernel<<<1024, 256, 0, stream>>>(q16, k16, vt16, o16);
  gemm_bt<1><<<dim3(8, 32), 256, 0, stream>>>(o16, w2, nullptr, out, proj_b, 4096, 1024, 1024);
}

// Round 2
// 173.154 us; speedup vs baseline: 1.2429x; 1.2429x over previous
//
#include <hip/hip_runtime.h>

#define DEVI __device__ __forceinline__

typedef __attribute__((ext_vector_type(8)))  short bh8;   // 8 x bf16 MFMA A/B frag
typedef __attribute__((ext_vector_type(4)))  float fx4;
typedef __attribute__((ext_vector_type(16))) float fx16;  // 32x32 MFMA C/D frag

DEVI unsigned short f2b(float f){            // fp32 -> bf16, RNE
  unsigned u = __float_as_uint(f);
  u += 0x7FFFu + ((u >> 16) & 1u);
  return (unsigned short)(u >> 16);
}
DEVI float b2f(unsigned short b){ return __uint_as_float(((unsigned)b) << 16); }

DEVI unsigned cvtpk(float a, float b){       // pack 2 f32 -> 2 bf16 (RNE), 1 inst
  unsigned r;
  asm("v_cvt_pk_bf16_f32 %0, %1, %2" : "=v"(r) : "v"(a), "v"(b));
  return r;
}

typedef __attribute__((address_space(1))) const void gvoid;
typedef __attribute__((address_space(3))) void svoid;
DEVI void gload16(const void* g, void* l){
  __builtin_amdgcn_global_load_lds((gvoid*)g, (svoid*)l, 16, 0, 0);
}

union pfu { unsigned u[4]; bh8 v; };

// ---------------------------------------------------------------- casts
__global__ __launch_bounds__(256) void cast_kernel(const float* __restrict__ in,
                                                   unsigned short* __restrict__ out, int n4){
  int i = blockIdx.x * 256 + threadIdx.x;
  if (i >= n4) return;
  float4 v = ((const float4*)in)[i];
  short4 r;
  r.x = (short)f2b(v.x); r.y = (short)f2b(v.y);
  r.z = (short)f2b(v.z); r.w = (short)f2b(v.w);
  ((short4*)out)[i] = r;
}

// -------------------------------------------------------------- rope table
// ct/st[pos*32 + j] = cos/sin(pos * theta^(-j/32)), pos in [0,1024), j in [0,32)
__global__ __launch_bounds__(256) void rope_table(float* __restrict__ ct, float* __restrict__ st){
  int i = blockIdx.x * 256 + threadIdx.x;   // 32768
  int pos = i >> 5, j = i & 31;
  float freq = __expf(-(float)j * 0.28782313662425576f);  // ln(10000)/32
  float sv, cv; sincosf((float)pos * freq, &sv, &cv);
  ct[i] = cv; st[i] = sv;
}

// ------------------------------------------------- bf16 GEMM: C = A * B^T
template<int MODE>
__global__ __launch_bounds__(256) void gemm_bt(
    const unsigned short* __restrict__ A, const unsigned short* __restrict__ B,
    unsigned short* __restrict__ Cb, float* __restrict__ Cf,
    const float* __restrict__ bias, int M, int N, int K)
{
  __shared__ short As[4096];  // [128][32] bf16
  __shared__ short Bs[4096];
  const int t = threadIdx.x, wv = t >> 6, ln = t & 63, lr = ln & 15, lg = ln >> 4;
  const int bm = blockIdx.y << 7, bn = blockIdx.x << 7;
  const int wr = wv >> 1, wc = wv & 1;
  const fx4 fz = {0.f, 0.f, 0.f, 0.f};
  fx4 acc[4][4];
#pragma unroll
  for (int i = 0; i < 4; i++)
#pragma unroll
    for (int j = 0; j < 4; j++) acc[i][j] = fz;

  for (int k0 = 0; k0 < K; k0 += 32){
#pragma unroll
    for (int i = 0; i < 2; i++){
      int c = i * 256 + t;
      int row = c >> 2, col = (c & 3) << 3;
      gload16(A + (size_t)(bm + row) * K + k0 + col, As + (i << 11) + (wv << 9));
      gload16(B + (size_t)(bn + row) * K + k0 + col, Bs + (i << 11) + (wv << 9));
    }
    __syncthreads();
    bh8 af[4], bf[4];
#pragma unroll
    for (int mi = 0; mi < 4; mi++) af[mi] = *(const bh8*)&As[(wr*64 + mi*16 + lr)*32 + lg*8];
#pragma unroll
    for (int ni = 0; ni < 4; ni++) bf[ni] = *(const bh8*)&Bs[(wc*64 + ni*16 + lr)*32 + lg*8];
#pragma unroll
    for (int mi = 0; mi < 4; mi++)
#pragma unroll
      for (int ni = 0; ni < 4; ni++)
        acc[mi][ni] = __builtin_amdgcn_mfma_f32_16x16x32_bf16(af[mi], bf[ni], acc[mi][ni], 0, 0, 0);
    __syncthreads();
  }
#pragma unroll
  for (int mi = 0; mi < 4; mi++)
#pragma unroll
    for (int ni = 0; ni < 4; ni++){
      int col = bn + wc*64 + ni*16 + lr;
#pragma unroll
      for (int r = 0; r < 4; r++){
        int row = bm + wr*64 + mi*16 + lg*4 + r;
        float v = acc[mi][ni][r];
        if constexpr (MODE == 1) Cf[(size_t)row * N + col] = v + bias[col];
        else                     Cb[(size_t)row * N + col] = (short)f2b(v);
      }
    }
}

// ---------------------------- LayerNorm(q,k over HD=64) + RoPE + v-transpose
// q output pre-scaled by 0.125*log2(e) so attention scores land in exp2-domain.
#define QSCALE 0.18033688011112042f
__global__ __launch_bounds__(256) void lnrope_kernel(
    const unsigned short* __restrict__ qkv,
    const float* __restrict__ qw, const float* __restrict__ qb,
    const float* __restrict__ kw, const float* __restrict__ kb,
    const float* __restrict__ ct, const float* __restrict__ st,
    unsigned short* __restrict__ qo, unsigned short* __restrict__ ko,
    unsigned short* __restrict__ vt)
{
  __shared__ short vl[64][66];
  const int t = threadIdx.x, wv = t >> 6, ln = t & 63;
  const int nc = blockIdx.x & 31, h = (blockIdx.x >> 5) & 15, b = blockIdx.x >> 9;
  const int j = ln & 31;
  const float gwq = qw[ln], gbq = qb[ln], gwk = kw[ln], gbk = kb[ln];
  const float sgn = (ln < 32) ? -1.0f : 1.0f;
  const size_t obase0 = ((size_t)(b*16 + h)) * 2048 * 64;
#pragma unroll 1
  for (int it = 0; it < 16; ++it){
    int nl = wv*16 + it;
    int n  = nc*64 + nl;
    size_t base = ((size_t)(b*2048 + n)) * 3072 + h*64 + ln;
    float qv = b2f(qkv[base]);
    float kv = b2f(qkv[base + 1024]);
    float vv = b2f(qkv[base + 2048]);
    float s1 = qv, s2 = qv*qv, s3 = kv, s4 = kv*kv;
#pragma unroll
    for (int off = 32; off; off >>= 1){
      s1 += __shfl_xor(s1, off); s2 += __shfl_xor(s2, off);
      s3 += __shfl_xor(s3, off); s4 += __shfl_xor(s4, off);
    }
    float mq = s1 * (1.f/64.f), mk = s3 * (1.f/64.f);
    float rq = rsqrtf(s2*(1.f/64.f) - mq*mq + 1e-5f);
    float rk = rsqrtf(s4*(1.f/64.f) - mk*mk + 1e-5f);
    float qn = (qv - mq) * rq * gwq + gbq;
    float kn = (kv - mk) * rk * gwk + gbk;
    int pos = n & 1023;                 // positions restart at n/2
    float cv = ct[pos*32 + j], sv = st[pos*32 + j];
    float qp = __shfl_xor(qn, 32);
    float kp = __shfl_xor(kn, 32);
    size_t ob = obase0 + (size_t)n*64 + ln;
    qo[ob] = f2b((qn*cv + sgn*qp*sv) * QSCALE);
    ko[ob] = f2b(kn*cv + sgn*kp*sv);
    vl[ln][nl] = (short)f2b(vv);
  }
  __syncthreads();
  int d = t >> 2, seg = t & 3;
  size_t vb = (((size_t)(b*16 + h))*64 + d) * 2048 + nc*64 + seg*16;
#pragma unroll
  for (int u = 0; u < 4; ++u){
    short4 pk;
    pk.x = vl[d][seg*16 + u*4 + 0]; pk.y = vl[d][seg*16 + u*4 + 1];
    pk.z = vl[d][seg*16 + u*4 + 2]; pk.w = vl[d][seg*16 + u*4 + 3];
    *(short4*)&vt[vb + u*4] = pk;
  }
}

// ------------------------------------------------------------ flash attention
// Swapped-QK^T 32x32 structure: S^T = mfma(K, Q); each lane owns one q-column.
// q: pre-scaled by 0.125*log2e (exp2-domain). 4 waves x 32 q-rows; KVBLK=64.
// LDS: K[64kv][64d], V^T[64d][64kv], both 16B-slot XOR-swizzled; double-buffered.
__global__ __launch_bounds__(256) void attn_kernel(
    const unsigned short* __restrict__ qg, const unsigned short* __restrict__ kg,
    const unsigned short* __restrict__ vg, unsigned short* __restrict__ og)
{
  __shared__ char sm[32768];   // 2 x (K 8KB + V 8KB); epilogue bounce reuses [0,17408)
  const int t = threadIdx.x, wv = t >> 6, ln = t & 63, lq = ln & 31, hi = ln >> 5;
  // XCD-grouped bijective swizzle (512 blocks, 64/XCD -> 4 heads' K/V per L2)
  const int swz = ((blockIdx.x & 7) << 6) | (blockIdx.x >> 3);
  const int bh = swz >> 4, q0 = (swz & 15) << 7;
  const unsigned short* kbase = kg + ((size_t)bh << 17);
  const unsigned short* vbase = vg + ((size_t)bh << 17);
  const size_t qrow = ((size_t)bh << 11) + q0 + wv*32 + lq;
  bh8 qf[4];
#pragma unroll
  for (int s2 = 0; s2 < 4; s2++) qf[s2] = *(const bh8*)&qg[qrow*64 + s2*16 + hi*8];

  fx16 o0, o1;
#pragma unroll
  for (int i = 0; i < 16; i++){ o0[i] = 0.f; o1[i] = 0.f; }
  float m_r = -1e30f, l_r = 0.f;
  const bool qfirst = (q0 < 1024);
  const int swsl = lq & 7;       // swizzle key for this lane's LDS rows

#define STAGE(buf, kt) do{                                                        \
  _Pragma("unroll")                                                               \
  for (int i_ = 0; i_ < 2; i_++){                                                 \
    int c_ = i_*256 + t;                                                          \
    int row_ = c_ >> 3, sl_ = (c_ & 7) ^ (row_ & 7);                              \
    gload16(kbase + (size_t)((kt) + row_)*64 + sl_*8,                             \
            sm + (buf)*16384 + i_*4096 + wv*1024);                                \
    gload16(vbase + (size_t)row_*2048 + (kt) + sl_*8,                             \
            sm + (buf)*16384 + 8192 + i_*4096 + wv*1024);                         \
  } }while(0)

  STAGE(0, 0);
  __syncthreads();
  for (int tile = 0; tile < 32; ++tile){
    const int cur = tile & 1;
    if (tile < 31) STAGE(cur ^ 1, (tile + 1)*64);
    const char* Kc = sm + cur*16384;
    const char* Vc = Kc + 8192;
    // ---- S^T = K · Q^T  (exp2-domain; bias folded into C-init: log2(0.5) = -1)
    const float bias2 = (qfirst != (tile < 16)) ? -1.0f : 0.0f;
    fx16 sA, sB;
#pragma unroll
    for (int i = 0; i < 16; i++){ sA[i] = bias2; sB[i] = bias2; }
#pragma unroll
    for (int s2 = 0; s2 < 4; s2++){
      const int slot = s2*2 + hi;
      bh8 kf0 = *(const bh8*)(Kc + lq*128        + ((slot ^ swsl) << 4));
      bh8 kf1 = *(const bh8*)(Kc + (32+lq)*128   + ((slot ^ swsl) << 4));
      sA = __builtin_amdgcn_mfma_f32_32x32x16_bf16(kf0, qf[s2], sA, 0, 0, 0);
      sB = __builtin_amdgcn_mfma_f32_32x32x16_bf16(kf1, qf[s2], sB, 0, 0, 0);
    }
    // ---- online softmax, lane-local (one q-column per lane pair)
    float pm = -1e30f;
#pragma unroll
    for (int i = 0; i < 16; i++) pm = fmaxf(pm, fmaxf(sA[i], sB[i]));
    pm = fmaxf(pm, __shfl_xor(pm, 32));
    if (__any(pm > m_r + 11.0f)){          // defer-max (T13), base-2 threshold
      float mn = fmaxf(m_r, pm);
      float cr = exp2f(m_r - mn);
      m_r = mn; l_r *= cr;
#pragma unroll
      for (int i = 0; i < 16; i++){ o0[i] *= cr; o1[i] *= cr; }
    }
    float sum = 0.f;
#pragma unroll
    for (int i = 0; i < 16; i++){
      sA[i] = exp2f(sA[i] - m_r);
      sB[i] = exp2f(sB[i] - m_r);
      sum += sA[i] + sB[i];
    }
    sum += __shfl_xor(sum, 32);
    l_r += sum;
    // ---- P -> bf16 B-fragments in-register (cvt_pk + permlane32_swap)
    bh8 pf[4];
#define MKPF(dst, sv, base) do{                                                   \
    unsigned c0 = cvtpk(sv[base+0], sv[base+1]);                                  \
    unsigned c1 = cvtpk(sv[base+2], sv[base+3]);                                  \
    unsigned c2 = cvtpk(sv[base+4], sv[base+5]);                                  \
    unsigned c3 = cvtpk(sv[base+6], sv[base+7]);                                  \
    asm volatile("v_permlane32_swap_b32 %0, %1" : "+v"(c0), "+v"(c2));            \
    asm volatile("v_permlane32_swap_b32 %0, %1" : "+v"(c1), "+v"(c3));            \
    pfu u_; u_.u[0]=c0; u_.u[1]=c1; u_.u[2]=c2; u_.u[3]=c3; dst = u_.v; }while(0)
    MKPF(pf[0], sA, 0); MKPF(pf[1], sA, 8);
    MKPF(pf[2], sB, 0); MKPF(pf[3], sB, 8);
#undef MKPF
    // ---- O^T += V^T · P^T
#pragma unroll
    for (int kg2 = 0; kg2 < 4; kg2++){
      const int slot = kg2*2 + hi;
      bh8 vf0 = *(const bh8*)(Vc + lq*128      + ((slot ^ swsl) << 4));
      bh8 vf1 = *(const bh8*)(Vc + (32+lq)*128 + ((slot ^ swsl) << 4));
      o0 = __builtin_amdgcn_mfma_f32_32x32x16_bf16(vf0, pf[kg2], o0, 0, 0, 0);
      o1 = __builtin_amdgcn_mfma_f32_32x32x16_bf16(vf1, pf[kg2], o1, 0, 0, 0);
    }
    __syncthreads();
  }
#undef STAGE
  // ---- epilogue: O^T (d,q) -> row-major rows via padded LDS bounce (stride 68 shorts)
  const float inv = 1.0f / l_r;
  const int ql = wv*32 + lq;
#pragma unroll
  for (int j = 0; j < 8; j++){
    int d0 = ((2*j) & 3) + 8*(j >> 1) + 4*hi;
    unsigned w0 = cvtpk(o0[2*j]*inv, o0[2*j+1]*inv);
    unsigned w1 = cvtpk(o1[2*j]*inv, o1[2*j+1]*inv);
    *(unsigned*)(sm + ql*136 + d0*2)        = w0;
    *(unsigned*)(sm + ql*136 + (32 + d0)*2) = w1;
  }
  __syncthreads();
  {
    const int rw = t >> 1, hf = t & 1;
    const int b = bh >> 4, h = bh & 15;
    unsigned short* dst = og + ((size_t)b*2048 + q0 + rw)*1024 + h*64 + hf*32;
#pragma unroll
    for (int u = 0; u < 8; u++){
      short4 v4 = *(short4*)(sm + rw*136 + hf*64 + u*8);
      *(short4*)(dst + u*4) = v4;
    }
  }
}

// ---------------------------------------------------------------- launcher
extern "C" void kernel_launch(void* const* d_in, const int* in_sizes, int n_in,
                              void* d_out, int out_size, void* d_ws, size_t ws_size,
                              hipStream_t stream)
{
  const float* x      = (const float*)d_in[0];
  const float* qkv_w  = (const float*)d_in[1];
  const float* qn_w   = (const float*)d_in[2];
  const float* qn_b   = (const float*)d_in[3];
  const float* kn_w   = (const float*)d_in[4];
  const float* kn_b   = (const float*)d_in[5];
  const float* proj_w = (const float*)d_in[6];
  const float* proj_b = (const float*)d_in[7];
  float* out = (float*)d_out;

  unsigned short* x16   = (unsigned short*)d_ws;          // 4096*1024
  unsigned short* w1    = x16   + (size_t)4096*1024;      // 3072*1024
  unsigned short* w2    = w1    + (size_t)3072*1024;      // 1024*1024
  unsigned short* qkv16 = w2    + (size_t)1024*1024;      // 4096*3072
  unsigned short* q16   = qkv16 + (size_t)4096*3072;      // 2*16*2048*64
  unsigned short* k16   = q16   + (size_t)4194304;
  unsigned short* vt16  = k16   + (size_t)4194304;
  unsigned short* o16   = qkv16;                          // alias: qkv dead after lnrope
  float* ct = (float*)x16;                                // alias: x16 dead after QKV gemm
  float* st = ct + 32768;

  cast_kernel<<<4096, 256, 0, stream>>>(x,      x16, 1048576);
  cast_kernel<<<3072, 256, 0, stream>>>(qkv_w,  w1,   786432);
  cast_kernel<<<1024, 256, 0, stream>>>(proj_w, w2,   262144);
  gemm_bt<0><<<dim3(24, 32), 256, 0, stream>>>(x16, w1, qkv16, nullptr, nullptr, 4096, 3072, 1024);
  rope_table<<<128, 256, 0, stream>>>(ct, st);
  lnrope_kernel<<<1024, 256, 0, stream>>>(qkv16, qn_w, qn_b, kn_w, kn_b, ct, st, q16, k16, vt16);
  attn_kernel<<<512, 256, 0, stream>>>(q16, k16, vt16, o16);
  gemm_bt<1><<<dim3(8, 32), 256, 0, stream>>>(o16, w2, nullptr, out, proj_b, 4096, 1024, 1024);
}

// Round 3
// 155.865 us; speedup vs baseline: 1.3808x; 1.1109x over previous
//
#include <hip/hip_runtime.h>

#define DEVI __device__ __forceinline__

typedef __attribute__((ext_vector_type(8)))  short bh8;   // 8 x bf16 MFMA A/B frag
typedef __attribute__((ext_vector_type(4)))  float fx4;
typedef __attribute__((ext_vector_type(16))) float fx16;  // 32x32 MFMA C/D frag

DEVI unsigned short f2b(float f){            // fp32 -> bf16, RNE
  unsigned u = __float_as_uint(f);
  u += 0x7FFFu + ((u >> 16) & 1u);
  return (unsigned short)(u >> 16);
}
DEVI float b2f(unsigned short b){ return __uint_as_float(((unsigned)b) << 16); }

DEVI unsigned cvtpk(float a, float b){       // pack 2 f32 -> 2 bf16 (RNE), 1 inst
  unsigned r;
  asm("v_cvt_pk_bf16_f32 %0, %1, %2" : "=v"(r) : "v"(a), "v"(b));
  return r;
}
DEVI float fexp2(float x){                   // raw v_exp_f32 (2^x), no OCML guards
  float r;
  asm("v_exp_f32 %0, %1" : "=v"(r) : "v"(x));
  return r;
}

typedef __attribute__((address_space(1))) const void gvoid;
typedef __attribute__((address_space(3))) void svoid;
DEVI void gload16(const void* g, void* l){
  __builtin_amdgcn_global_load_lds((gvoid*)g, (svoid*)l, 16, 0, 0);
}

union pfu { unsigned u[4]; bh8 v; };

// ---------------------------------------------------------------- casts
__global__ __launch_bounds__(256) void cast_kernel(const float* __restrict__ in,
                                                   unsigned short* __restrict__ out, int n4){
  int i = blockIdx.x * 256 + threadIdx.x;
  if (i >= n4) return;
  float4 v = ((const float4*)in)[i];
  short4 r;
  r.x = (short)f2b(v.x); r.y = (short)f2b(v.y);
  r.z = (short)f2b(v.z); r.w = (short)f2b(v.w);
  ((short4*)out)[i] = r;
}

// -------------------------------------------------------------- rope table
__global__ __launch_bounds__(256) void rope_table(float* __restrict__ ct, float* __restrict__ st){
  int i = blockIdx.x * 256 + threadIdx.x;   // 32768
  int pos = i >> 5, j = i & 31;
  float freq = __expf(-(float)j * 0.28782313662425576f);  // ln(10000)/32
  float sv, cv; sincosf((float)pos * freq, &sv, &cv);
  ct[i] = cv; st[i] = sv;
}

// ------------------------------------------------- bf16 GEMM: C = A * B^T
template<int MODE>
__global__ __launch_bounds__(256) void gemm_bt(
    const unsigned short* __restrict__ A, const unsigned short* __restrict__ B,
    unsigned short* __restrict__ Cb, float* __restrict__ Cf,
    const float* __restrict__ bias, int M, int N, int K)
{
  __shared__ short As[4096];  // [128][32] bf16
  __shared__ short Bs[4096];
  const int t = threadIdx.x, wv = t >> 6, ln = t & 63, lr = ln & 15, lg = ln >> 4;
  // XCD-bijective swizzle, bx-major work order (B-panel locality per XCD L2)
  const int nbx = gridDim.x, nby = gridDim.y, nwg = nbx * nby;
  const int orig = blockIdx.y * nbx + blockIdx.x;
  const int w = (orig & 7) * (nwg >> 3) + (orig >> 3);
  const int bn = (w / nby) << 7, bm = (w % nby) << 7;
  const int wr = wv >> 1, wc = wv & 1;
  const fx4 fz = {0.f, 0.f, 0.f, 0.f};
  fx4 acc[4][4];
#pragma unroll
  for (int i = 0; i < 4; i++)
#pragma unroll
    for (int j = 0; j < 4; j++) acc[i][j] = fz;

  for (int k0 = 0; k0 < K; k0 += 32){
#pragma unroll
    for (int i = 0; i < 2; i++){
      int c = i * 256 + t;
      int row = c >> 2, col = (c & 3) << 3;
      gload16(A + (size_t)(bm + row) * K + k0 + col, As + (i << 11) + (wv << 9));
      gload16(B + (size_t)(bn + row) * K + k0 + col, Bs + (i << 11) + (wv << 9));
    }
    __syncthreads();
    bh8 af[4], bf[4];
#pragma unroll
    for (int mi = 0; mi < 4; mi++) af[mi] = *(const bh8*)&As[(wr*64 + mi*16 + lr)*32 + lg*8];
#pragma unroll
    for (int ni = 0; ni < 4; ni++) bf[ni] = *(const bh8*)&Bs[(wc*64 + ni*16 + lr)*32 + lg*8];
    __builtin_amdgcn_s_setprio(1);
#pragma unroll
    for (int mi = 0; mi < 4; mi++)
#pragma unroll
      for (int ni = 0; ni < 4; ni++)
        acc[mi][ni] = __builtin_amdgcn_mfma_f32_16x16x32_bf16(af[mi], bf[ni], acc[mi][ni], 0, 0, 0);
    __builtin_amdgcn_s_setprio(0);
    __syncthreads();
  }
#pragma unroll
  for (int mi = 0; mi < 4; mi++)
#pragma unroll
    for (int ni = 0; ni < 4; ni++){
      int col = bn + wc*64 + ni*16 + lr;
#pragma unroll
      for (int r = 0; r < 4; r++){
        int row = bm + wr*64 + mi*16 + lg*4 + r;
        float v = acc[mi][ni][r];
        if constexpr (MODE == 1) Cf[(size_t)row * N + col] = v + bias[col];
        else                     Cb[(size_t)row * N + col] = (short)f2b(v);
      }
    }
}

// ---------------------------- LayerNorm(q,k over HD=64) + RoPE + v-transpose
#define QSCALE 0.18033688011112042f
__global__ __launch_bounds__(256) void lnrope_kernel(
    const unsigned short* __restrict__ qkv,
    const float* __restrict__ qw, const float* __restrict__ qb,
    const float* __restrict__ kw, const float* __restrict__ kb,
    const float* __restrict__ ct, const float* __restrict__ st,
    unsigned short* __restrict__ qo, unsigned short* __restrict__ ko,
    unsigned short* __restrict__ vt)
{
  __shared__ short vl[64][66];
  const int t = threadIdx.x, wv = t >> 6, ln = t & 63;
  const int nc = blockIdx.x & 31, h = (blockIdx.x >> 5) & 15, b = blockIdx.x >> 9;
  const int j = ln & 31;
  const float gwq = qw[ln], gbq = qb[ln], gwk = kw[ln], gbk = kb[ln];
  const float sgn = (ln < 32) ? -1.0f : 1.0f;
  const size_t obase0 = ((size_t)(b*16 + h)) * 2048 * 64;
#pragma unroll 1
  for (int it = 0; it < 16; ++it){
    int nl = wv*16 + it;
    int n  = nc*64 + nl;
    size_t base = ((size_t)(b*2048 + n)) * 3072 + h*64 + ln;
    float qv = b2f(qkv[base]);
    float kv = b2f(qkv[base + 1024]);
    float vv = b2f(qkv[base + 2048]);
    float s1 = qv, s2 = qv*qv, s3 = kv, s4 = kv*kv;
#pragma unroll
    for (int off = 32; off; off >>= 1){
      s1 += __shfl_xor(s1, off); s2 += __shfl_xor(s2, off);
      s3 += __shfl_xor(s3, off); s4 += __shfl_xor(s4, off);
    }
    float mq = s1 * (1.f/64.f), mk = s3 * (1.f/64.f);
    float rq = rsqrtf(s2*(1.f/64.f) - mq*mq + 1e-5f);
    float rk = rsqrtf(s4*(1.f/64.f) - mk*mk + 1e-5f);
    float qn = (qv - mq) * rq * gwq + gbq;
    float kn = (kv - mk) * rk * gwk + gbk;
    int pos = n & 1023;                 // positions restart at n/2
    float cv = ct[pos*32 + j], sv = st[pos*32 + j];
    float qp = __shfl_xor(qn, 32);
    float kp = __shfl_xor(kn, 32);
    size_t ob = obase0 + (size_t)n*64 + ln;
    qo[ob] = f2b((qn*cv + sgn*qp*sv) * QSCALE);
    ko[ob] = f2b(kn*cv + sgn*kp*sv);
    vl[ln][nl] = (short)f2b(vv);
  }
  __syncthreads();
  int d = t >> 2, seg = t & 3;
  size_t vb = (((size_t)(b*16 + h))*64 + d) * 2048 + nc*64 + seg*16;
#pragma unroll
  for (int u = 0; u < 4; ++u){
    short4 pk;
    pk.x = vl[d][seg*16 + u*4 + 0]; pk.y = vl[d][seg*16 + u*4 + 1];
    pk.z = vl[d][seg*16 + u*4 + 2]; pk.w = vl[d][seg*16 + u*4 + 3];
    *(short4*)&vt[vb + u*4] = pk;
  }
}

// ------------------------------------------------------------ flash attention
// Swapped-QK^T 32x32: S^T = mfma(K, Q); lane-pair owns one q-column (exp2-domain).
__global__ __launch_bounds__(256) void attn_kernel(
    const unsigned short* __restrict__ qg, const unsigned short* __restrict__ kg,
    const unsigned short* __restrict__ vg, unsigned short* __restrict__ og)
{
  __shared__ char sm[32768];   // 2 x (K 8KB + V 8KB); epilogue bounce reuses [0,16896)
  const int t = threadIdx.x, wv = t >> 6, ln = t & 63, lq = ln & 31, hi = ln >> 5;
  const int swz = ((blockIdx.x & 7) << 6) | (blockIdx.x >> 3);
  const int bh = swz >> 4, q0 = (swz & 15) << 7;
  const unsigned short* kbase = kg + ((size_t)bh << 17);
  const unsigned short* vbase = vg + ((size_t)bh << 17);
  const size_t qrow = ((size_t)bh << 11) + q0 + wv*32 + lq;
  bh8 qf[4];
#pragma unroll
  for (int s2 = 0; s2 < 4; s2++) qf[s2] = *(const bh8*)&qg[qrow*64 + s2*16 + hi*8];

  fx16 o0, o1;
#pragma unroll
  for (int i = 0; i < 16; i++){ o0[i] = 0.f; o1[i] = 0.f; }
  float m_r = -1e30f, l_r = 0.f;
  const bool qfirst = (q0 < 1024);
  const int swsl = lq & 7;

#define STAGE(buf, kt) do{                                                        \
  _Pragma("unroll")                                                               \
  for (int i_ = 0; i_ < 2; i_++){                                                 \
    int c_ = i_*256 + t;                                                          \
    int row_ = c_ >> 3, sl_ = (c_ & 7) ^ (row_ & 7);                              \
    gload16(kbase + (size_t)((kt) + row_)*64 + sl_*8,                             \
            sm + (buf)*16384 + i_*4096 + wv*1024);                                \
    gload16(vbase + (size_t)row_*2048 + (kt) + sl_*8,                             \
            sm + (buf)*16384 + 8192 + i_*4096 + wv*1024);                         \
  } }while(0)

  STAGE(0, 0);
  __syncthreads();
  for (int tile = 0; tile < 32; ++tile){
    const int cur = tile & 1;
    if (tile < 31) STAGE(cur ^ 1, (tile + 1)*64);
    const char* Kc = sm + cur*16384;
    const char* Vc = Kc + 8192;
    // ---- S^T = K · Q^T  (bias folded into C-init: log2(0.5) = -1)
    const float bias2 = (qfirst != (tile < 16)) ? -1.0f : 0.0f;
    fx16 sA, sB;
#pragma unroll
    for (int i = 0; i < 16; i++){ sA[i] = bias2; sB[i] = bias2; }
    __builtin_amdgcn_s_setprio(1);
#pragma unroll
    for (int s2 = 0; s2 < 4; s2++){
      const int slot = s2*2 + hi;
      bh8 kf0 = *(const bh8*)(Kc + lq*128        + ((slot ^ swsl) << 4));
      bh8 kf1 = *(const bh8*)(Kc + (32+lq)*128   + ((slot ^ swsl) << 4));
      sA = __builtin_amdgcn_mfma_f32_32x32x16_bf16(kf0, qf[s2], sA, 0, 0, 0);
      sB = __builtin_amdgcn_mfma_f32_32x32x16_bf16(kf1, qf[s2], sB, 0, 0, 0);
    }
    __builtin_amdgcn_s_setprio(0);
    // ---- online softmax, lane-local
    float pm = -1e30f;
#pragma unroll
    for (int i = 0; i < 16; i++) pm = fmaxf(pm, fmaxf(sA[i], sB[i]));
    pm = fmaxf(pm, __shfl_xor(pm, 32));
    if (__any(pm > m_r + 11.0f)){          // defer-max (T13), base-2 threshold
      float mn = fmaxf(m_r, pm);
      float cr = fexp2(m_r - mn);
      m_r = mn; l_r *= cr;
#pragma unroll
      for (int i = 0; i < 16; i++){ o0[i] *= cr; o1[i] *= cr; }
    }
    float sum = 0.f;
#pragma unroll
    for (int i = 0; i < 16; i++){
      sA[i] = fexp2(sA[i] - m_r);
      sB[i] = fexp2(sB[i] - m_r);
      sum += sA[i] + sB[i];
    }
    sum += __shfl_xor(sum, 32);
    l_r += sum;
    // ---- P -> bf16 B-fragments in-register (cvt_pk + permlane32_swap)
    bh8 pf[4];
#define MKPF(dst, sv, base) do{                                                   \
    unsigned c0 = cvtpk(sv[base+0], sv[base+1]);                                  \
    unsigned c1 = cvtpk(sv[base+2], sv[base+3]);                                  \
    unsigned c2 = cvtpk(sv[base+4], sv[base+5]);                                  \
    unsigned c3 = cvtpk(sv[base+6], sv[base+7]);                                  \
    asm volatile("v_permlane32_swap_b32 %0, %1" : "+v"(c0), "+v"(c2));            \
    asm volatile("v_permlane32_swap_b32 %0, %1" : "+v"(c1), "+v"(c3));            \
    pfu u_; u_.u[0]=c0; u_.u[1]=c1; u_.u[2]=c2; u_.u[3]=c3; dst = u_.v; }while(0)
    MKPF(pf[0], sA, 0); MKPF(pf[1], sA, 8);
    MKPF(pf[2], sB, 0); MKPF(pf[3], sB, 8);
#undef MKPF
    // ---- O^T += V^T · P^T
    __builtin_amdgcn_s_setprio(1);
#pragma unroll
    for (int kg2 = 0; kg2 < 4; kg2++){
      const int slot = kg2*2 + hi;
      bh8 vf0 = *(const bh8*)(Vc + lq*128      + ((slot ^ swsl) << 4));
      bh8 vf1 = *(const bh8*)(Vc + (32+lq)*128 + ((slot ^ swsl) << 4));
      o0 = __builtin_amdgcn_mfma_f32_32x32x16_bf16(vf0, pf[kg2], o0, 0, 0, 0);
      o1 = __builtin_amdgcn_mfma_f32_32x32x16_bf16(vf1, pf[kg2], o1, 0, 0, 0);
    }
    __builtin_amdgcn_s_setprio(0);
    __syncthreads();
  }
#undef STAGE
  // ---- epilogue: O^T (d,q) -> row-major rows via LDS bounce (stride 132B, 2-way free)
  const float inv = 1.0f / l_r;
  const int ql = wv*32 + lq;
#pragma unroll
  for (int j = 0; j < 8; j++){
    int d0 = ((2*j) & 3) + 8*(j >> 1) + 4*hi;
    unsigned w0 = cvtpk(o0[2*j]*inv, o0[2*j+1]*inv);
    unsigned w1 = cvtpk(o1[2*j]*inv, o1[2*j+1]*inv);
    *(unsigned*)(sm + ql*132 + d0*2)        = w0;
    *(unsigned*)(sm + ql*132 + (32 + d0)*2) = w1;
  }
  __syncthreads();
  {
    const int rw = t >> 1, hf = t & 1;
    const int b = bh >> 4, h = bh & 15;
    unsigned short* dst = og + ((size_t)b*2048 + q0 + rw)*1024 + h*64 + hf*32;
#pragma unroll
    for (int u = 0; u < 8; u++){
      short4 v4 = *(short4*)(sm + rw*132 + hf*64 + u*8);
      *(short4*)(dst + u*4) = v4;
    }
  }
}

// ---------------------------------------------------------------- launcher
extern "C" void kernel_launch(void* const* d_in, const int* in_sizes, int n_in,
                              void* d_out, int out_size, void* d_ws, size_t ws_size,
                              hipStream_t stream)
{
  const float* x      = (const float*)d_in[0];
  const float* qkv_w  = (const float*)d_in[1];
  const float* qn_w   = (const float*)d_in[2];
  const float* qn_b   = (const float*)d_in[3];
  const float* kn_w   = (const float*)d_in[4];
  const float* kn_b   = (const float*)d_in[5];
  const float* proj_w = (const float*)d_in[6];
  const float* proj_b = (const float*)d_in[7];
  float* out = (float*)d_out;

  unsigned short* x16   = (unsigned short*)d_ws;          // 4096*1024
  unsigned short* w1    = x16   + (size_t)4096*1024;      // 3072*1024
  unsigned short* w2    = w1    + (size_t)3072*1024;      // 1024*1024
  unsigned short* qkv16 = w2    + (size_t)1024*1024;      // 4096*3072
  unsigned short* q16   = qkv16 + (size_t)4096*3072;      // 2*16*2048*64
  unsigned short* k16   = q16   + (size_t)4194304;
  unsigned short* vt16  = k16   + (size_t)4194304;
  unsigned short* o16   = qkv16;                          // alias: qkv dead after lnrope
  float* ct = (float*)x16;                                // alias: x16 dead after QKV gemm
  float* st = ct + 32768;

  cast_kernel<<<4096, 256, 0, stream>>>(x,      x16, 1048576);
  cast_kernel<<<3072, 256, 0, stream>>>(qkv_w,  w1,   786432);
  cast_kernel<<<1024, 256, 0, stream>>>(proj_w, w2,   262144);
  gemm_bt<0><<<dim3(24, 32), 256, 0, stream>>>(x16, w1, qkv16, nullptr, nullptr, 4096, 3072, 1024);
  rope_table<<<128, 256, 0, stream>>>(ct, st);
  lnrope_kernel<<<1024, 256, 0, stream>>>(qkv16, qn_w, qn_b, kn_w, kn_b, ct, st, q16, k16, vt16);
  attn_kernel<<<512, 256, 0, stream>>>(q16, k16, vt16, o16);
  gemm_bt<1><<<dim3(8, 32), 256, 0, stream>>>(o16, w2, nullptr, out, proj_b, 4096, 1024, 1024);
}

// Round 4
// 149.183 us; speedup vs baseline: 1.4427x; 1.0448x over previous
//
#include <hip/hip_runtime.h>

#define DEVI __device__ __forceinline__

typedef __attribute__((ext_vector_type(8)))  short bh8;   // 8 x bf16 MFMA A/B frag
typedef __attribute__((ext_vector_type(4)))  float fx4;
typedef __attribute__((ext_vector_type(16))) float fx16;  // 32x32 MFMA C/D frag

DEVI unsigned short f2b(float f){            // fp32 -> bf16, RNE
  unsigned u = __float_as_uint(f);
  u += 0x7FFFu + ((u >> 16) & 1u);
  return (unsigned short)(u >> 16);
}
DEVI float b2f(unsigned short b){ return __uint_as_float(((unsigned)b) << 16); }

DEVI unsigned cvtpk(float a, float b){       // pack 2 f32 -> 2 bf16 (RNE), 1 inst
  unsigned r;
  asm("v_cvt_pk_bf16_f32 %0, %1, %2" : "=v"(r) : "v"(a), "v"(b));
  return r;
}
DEVI float fexp2(float x){                   // raw v_exp_f32 (2^x), no OCML guards
  float r;
  asm("v_exp_f32 %0, %1" : "=v"(r) : "v"(x));
  return r;
}

typedef __attribute__((address_space(1))) const void gvoid;
typedef __attribute__((address_space(3))) void svoid;
DEVI void gload16(const void* g, void* l){
  __builtin_amdgcn_global_load_lds((gvoid*)g, (svoid*)l, 16, 0, 0);
}

union pfu { unsigned u[4]; bh8 v; };

// ------------------------------------------------------------ fused cast x3
__global__ __launch_bounds__(256) void cast3_kernel(
    const float* __restrict__ x, const float* __restrict__ w1f, const float* __restrict__ w2f,
    unsigned short* __restrict__ x16, unsigned short* __restrict__ w1, unsigned short* __restrict__ w2)
{
  int i = blockIdx.x * 256 + threadIdx.x;   // 2097152 float4s total
  const float* src; unsigned short* dst; int off;
  if (i < 1048576)      { src = x;   dst = x16; off = i; }
  else if (i < 1835008) { src = w1f; dst = w1;  off = i - 1048576; }
  else                  { src = w2f; dst = w2;  off = i - 1835008; }
  float4 v = ((const float4*)src)[off];
  short4 r;
  r.x = (short)f2b(v.x); r.y = (short)f2b(v.y);
  r.z = (short)f2b(v.z); r.w = (short)f2b(v.w);
  ((short4*)dst)[off] = r;
}

// -------------------------------------------------------------- rope table
__global__ __launch_bounds__(256) void rope_table(float* __restrict__ ct, float* __restrict__ st){
  int i = blockIdx.x * 256 + threadIdx.x;   // 32768
  int pos = i >> 5, j = i & 31;
  float freq = __expf(-(float)j * 0.28782313662425576f);  // ln(10000)/32
  float sv, cv; sincosf((float)pos * freq, &sv, &cv);
  ct[i] = cv; st[i] = sv;
}

// ------------------------------------------------- bf16 GEMM: C = A * B^T
template<int MODE>
__global__ __launch_bounds__(256) void gemm_bt(
    const unsigned short* __restrict__ A, const unsigned short* __restrict__ B,
    unsigned short* __restrict__ Cb, float* __restrict__ Cf,
    const float* __restrict__ bias, int M, int N, int K)
{
  __shared__ short As[4096];  // [128][32] bf16
  __shared__ short Bs[4096];
  const int t = threadIdx.x, wv = t >> 6, ln = t & 63, lr = ln & 15, lg = ln >> 4;
  const int nbx = gridDim.x, nby = gridDim.y, nwg = nbx * nby;
  const int orig = blockIdx.y * nbx + blockIdx.x;
  const int w = (orig & 7) * (nwg >> 3) + (orig >> 3);
  const int bn = (w / nby) << 7, bm = (w % nby) << 7;
  const int wr = wv >> 1, wc = wv & 1;
  const fx4 fz = {0.f, 0.f, 0.f, 0.f};
  fx4 acc[4][4];
#pragma unroll
  for (int i = 0; i < 4; i++)
#pragma unroll
    for (int j = 0; j < 4; j++) acc[i][j] = fz;

  for (int k0 = 0; k0 < K; k0 += 32){
#pragma unroll
    for (int i = 0; i < 2; i++){
      int c = i * 256 + t;
      int row = c >> 2, col = (c & 3) << 3;
      gload16(A + (size_t)(bm + row) * K + k0 + col, As + (i << 11) + (wv << 9));
      gload16(B + (size_t)(bn + row) * K + k0 + col, Bs + (i << 11) + (wv << 9));
    }
    __syncthreads();
    bh8 af[4], bf[4];
#pragma unroll
    for (int mi = 0; mi < 4; mi++) af[mi] = *(const bh8*)&As[(wr*64 + mi*16 + lr)*32 + lg*8];
#pragma unroll
    for (int ni = 0; ni < 4; ni++) bf[ni] = *(const bh8*)&Bs[(wc*64 + ni*16 + lr)*32 + lg*8];
    __builtin_amdgcn_s_setprio(1);
#pragma unroll
    for (int mi = 0; mi < 4; mi++)
#pragma unroll
      for (int ni = 0; ni < 4; ni++)
        acc[mi][ni] = __builtin_amdgcn_mfma_f32_16x16x32_bf16(af[mi], bf[ni], acc[mi][ni], 0, 0, 0);
    __builtin_amdgcn_s_setprio(0);
    __syncthreads();
  }
#pragma unroll
  for (int mi = 0; mi < 4; mi++)
#pragma unroll
    for (int ni = 0; ni < 4; ni++){
      int col = bn + wc*64 + ni*16 + lr;
#pragma unroll
      for (int r = 0; r < 4; r++){
        int row = bm + wr*64 + mi*16 + lg*4 + r;
        float v = acc[mi][ni][r];
        if constexpr (MODE == 1) Cf[(size_t)row * N + col] = v + bias[col];
        else                     Cb[(size_t)row * N + col] = (short)f2b(v);
      }
    }
}

// ---------------------------- LayerNorm(q,k over HD=64) + RoPE + v-transpose
#define QSCALE 0.18033688011112042f
__global__ __launch_bounds__(256) void lnrope_kernel(
    const unsigned short* __restrict__ qkv,
    const float* __restrict__ qw, const float* __restrict__ qb,
    const float* __restrict__ kw, const float* __restrict__ kb,
    const float* __restrict__ ct, const float* __restrict__ st,
    unsigned short* __restrict__ qo, unsigned short* __restrict__ ko,
    unsigned short* __restrict__ vt)
{
  __shared__ short vl[64][66];
  const int t = threadIdx.x, wv = t >> 6, ln = t & 63;
  const int nc = blockIdx.x & 31, h = (blockIdx.x >> 5) & 15, b = blockIdx.x >> 9;
  const int j = ln & 31;
  const float gwq = qw[ln], gbq = qb[ln], gwk = kw[ln], gbk = kb[ln];
  const float sgn = (ln < 32) ? -1.0f : 1.0f;
  const size_t obase0 = ((size_t)(b*16 + h)) * 2048 * 64;
#pragma unroll 1
  for (int it = 0; it < 16; ++it){
    int nl = wv*16 + it;
    int n  = nc*64 + nl;
    size_t base = ((size_t)(b*2048 + n)) * 3072 + h*64 + ln;
    float qv = b2f(qkv[base]);
    float kv = b2f(qkv[base + 1024]);
    float vv = b2f(qkv[base + 2048]);
    float s1 = qv, s2 = qv*qv, s3 = kv, s4 = kv*kv;
#pragma unroll
    for (int off = 32; off; off >>= 1){
      s1 += __shfl_xor(s1, off); s2 += __shfl_xor(s2, off);
      s3 += __shfl_xor(s3, off); s4 += __shfl_xor(s4, off);
    }
    float mq = s1 * (1.f/64.f), mk = s3 * (1.f/64.f);
    float rq = rsqrtf(s2*(1.f/64.f) - mq*mq + 1e-5f);
    float rk = rsqrtf(s4*(1.f/64.f) - mk*mk + 1e-5f);
    float qn = (qv - mq) * rq * gwq + gbq;
    float kn = (kv - mk) * rk * gwk + gbk;
    int pos = n & 1023;                 // positions restart at n/2
    float cv = ct[pos*32 + j], sv = st[pos*32 + j];
    float qp = __shfl_xor(qn, 32);
    float kp = __shfl_xor(kn, 32);
    size_t ob = obase0 + (size_t)n*64 + ln;
    qo[ob] = f2b((qn*cv + sgn*qp*sv) * QSCALE);
    ko[ob] = f2b(kn*cv + sgn*kp*sv);
    vl[ln][nl] = (short)f2b(vv);
  }
  __syncthreads();
  int d = t >> 2, seg = t & 3;
  size_t vb = (((size_t)(b*16 + h))*64 + d) * 2048 + nc*64 + seg*16;
#pragma unroll
  for (int u = 0; u < 4; ++u){
    short4 pk;
    pk.x = vl[d][seg*16 + u*4 + 0]; pk.y = vl[d][seg*16 + u*4 + 1];
    pk.z = vl[d][seg*16 + u*4 + 2]; pk.w = vl[d][seg*16 + u*4 + 3];
    *(short4*)&vt[vb + u*4] = pk;
  }
}

// ------------------------------------------------------------ flash attention
// Swapped-QK^T 32x32; triple-buffered LDS, counted vmcnt(4), raw s_barrier.
// Per tile each wave issues exactly 4 gload_lds -> steady-state vmcnt(4)
// leaves next tile's loads in flight across the barrier (T3/T4).
__global__ __launch_bounds__(256, 2) void attn_kernel(
    const unsigned short* __restrict__ qg, const unsigned short* __restrict__ kg,
    const unsigned short* __restrict__ vg, unsigned short* __restrict__ og)
{
  __shared__ char sm[49152];   // 3 x (K 8KB + V 8KB); epilogue bounce reuses [0,16896)
  const int t = threadIdx.x, wv = t >> 6, ln = t & 63, lq = ln & 31, hi = ln >> 5;
  const int swz = ((blockIdx.x & 7) << 6) | (blockIdx.x >> 3);
  const int bh = swz >> 4, q0 = (swz & 15) << 7;
  const unsigned short* kbase = kg + ((size_t)bh << 17);
  const unsigned short* vbase = vg + ((size_t)bh << 17);
  const size_t qrow = ((size_t)bh << 11) + q0 + wv*32 + lq;
  bh8 qf[4];                                  // issued FIRST (oldest in vmcnt FIFO)
#pragma unroll
  for (int s2 = 0; s2 < 4; s2++) qf[s2] = *(const bh8*)&qg[qrow*64 + s2*16 + hi*8];

  fx16 o0, o1;
#pragma unroll
  for (int i = 0; i < 16; i++){ o0[i] = 0.f; o1[i] = 0.f; }
  float m_r = -1e30f, l_r = 0.f;
  const bool qfirst = (q0 < 1024);
  const int swsl = lq & 7;

#define STAGE(dst, kt) do{                                                        \
  _Pragma("unroll")                                                               \
  for (int i_ = 0; i_ < 2; i_++){                                                 \
    int c_ = i_*256 + t;                                                          \
    int row_ = c_ >> 3, sl_ = (c_ & 7) ^ (row_ & 7);                              \
    gload16(kbase + (size_t)((kt) + row_)*64 + sl_*8, (dst) + i_*4096 + wv*1024); \
    gload16(vbase + (size_t)row_*2048 + (kt) + sl_*8,                             \
            (dst) + 8192 + i_*4096 + wv*1024);                                    \
  } }while(0)

  char* p0 = sm; char* p1 = sm + 16384; char* p2 = sm + 32768;
  STAGE(p0, 0);
  STAGE(p1, 64);
  // qf(4) + stage0(4) retired; stage1 stays in flight
  asm volatile("s_waitcnt vmcnt(4)" ::: "memory");
  __builtin_amdgcn_s_barrier();
  __builtin_amdgcn_sched_barrier(0);

  for (int tile = 0; tile < 32; ++tile){
    if (tile < 30) STAGE(p2, (tile + 2)*64);
    const char* Kc = p0;
    const char* Vc = p0 + 8192;
    // ---- S^T = K · Q^T  (bias folded into C-init: log2(0.5) = -1)
    const float bias2 = (qfirst != (tile < 16)) ? -1.0f : 0.0f;
    fx16 sA, sB;
#pragma unroll
    for (int i = 0; i < 16; i++){ sA[i] = bias2; sB[i] = bias2; }
    __builtin_amdgcn_s_setprio(1);
#pragma unroll
    for (int s2 = 0; s2 < 4; s2++){
      const int slot = s2*2 + hi;
      bh8 kf0 = *(const bh8*)(Kc + lq*128        + ((slot ^ swsl) << 4));
      bh8 kf1 = *(const bh8*)(Kc + (32+lq)*128   + ((slot ^ swsl) << 4));
      sA = __builtin_amdgcn_mfma_f32_32x32x16_bf16(kf0, qf[s2], sA, 0, 0, 0);
      sB = __builtin_amdgcn_mfma_f32_32x32x16_bf16(kf1, qf[s2], sB, 0, 0, 0);
    }
    __builtin_amdgcn_s_setprio(0);
    // ---- V fragments issued EARLY: latency hides under softmax
    bh8 vf0[4], vf1[4];
#pragma unroll
    for (int kg2 = 0; kg2 < 4; kg2++){
      const int slot = kg2*2 + hi;
      vf0[kg2] = *(const bh8*)(Vc + lq*128      + ((slot ^ swsl) << 4));
      vf1[kg2] = *(const bh8*)(Vc + (32+lq)*128 + ((slot ^ swsl) << 4));
    }
    // ---- online softmax, lane-local
    float pm = -1e30f;
#pragma unroll
    for (int i = 0; i < 16; i++) pm = fmaxf(pm, fmaxf(sA[i], sB[i]));
    pm = fmaxf(pm, __shfl_xor(pm, 32));
    if (__any(pm > m_r + 11.0f)){          // defer-max (T13), base-2 threshold
      float mn = fmaxf(m_r, pm);
      float cr = fexp2(m_r - mn);
      m_r = mn; l_r *= cr;
#pragma unroll
      for (int i = 0; i < 16; i++){ o0[i] *= cr; o1[i] *= cr; }
    }
    float sum = 0.f;
#pragma unroll
    for (int i = 0; i < 16; i++){
      sA[i] = fexp2(sA[i] - m_r);
      sB[i] = fexp2(sB[i] - m_r);
      sum += sA[i] + sB[i];
    }
    sum += __shfl_xor(sum, 32);
    l_r += sum;
    // ---- P -> bf16 B-fragments in-register (cvt_pk + permlane32_swap)
    bh8 pf[4];
#define MKPF(dst, sv, base) do{                                                   \
    unsigned c0 = cvtpk(sv[base+0], sv[base+1]);                                  \
    unsigned c1 = cvtpk(sv[base+2], sv[base+3]);                                  \
    unsigned c2 = cvtpk(sv[base+4], sv[base+5]);                                  \
    unsigned c3 = cvtpk(sv[base+6], sv[base+7]);                                  \
    asm volatile("v_permlane32_swap_b32 %0, %1" : "+v"(c0), "+v"(c2));            \
    asm volatile("v_permlane32_swap_b32 %0, %1" : "+v"(c1), "+v"(c3));            \
    pfu u_; u_.u[0]=c0; u_.u[1]=c1; u_.u[2]=c2; u_.u[3]=c3; dst = u_.v; }while(0)
    MKPF(pf[0], sA, 0); MKPF(pf[1], sA, 8);
    MKPF(pf[2], sB, 0); MKPF(pf[3], sB, 8);
#undef MKPF
    // ---- O^T += V^T · P^T (V already in regs)
    __builtin_amdgcn_s_setprio(1);
#pragma unroll
    for (int kg2 = 0; kg2 < 4; kg2++){
      o0 = __builtin_amdgcn_mfma_f32_32x32x16_bf16(vf0[kg2], pf[kg2], o0, 0, 0, 0);
      o1 = __builtin_amdgcn_mfma_f32_32x32x16_bf16(vf1[kg2], pf[kg2], o1, 0, 0, 0);
    }
    __builtin_amdgcn_s_setprio(0);
    // ---- counted drain: next tile's 4 loads complete, tile+2's stay in flight
    if (tile < 30) asm volatile("s_waitcnt vmcnt(4) lgkmcnt(0)" ::: "memory");
    else           asm volatile("s_waitcnt vmcnt(0) lgkmcnt(0)" ::: "memory");
    __builtin_amdgcn_s_barrier();
    __builtin_amdgcn_sched_barrier(0);
    char* tmp = p0; p0 = p1; p1 = p2; p2 = tmp;
  }
#undef STAGE
  // ---- epilogue: O^T (d,q) -> row-major rows via LDS bounce (stride 132B)
  const float inv = 1.0f / l_r;
  const int ql = wv*32 + lq;
#pragma unroll
  for (int j = 0; j < 8; j++){
    int d0 = ((2*j) & 3) + 8*(j >> 1) + 4*hi;
    unsigned w0 = cvtpk(o0[2*j]*inv, o0[2*j+1]*inv);
    unsigned w1 = cvtpk(o1[2*j]*inv, o1[2*j+1]*inv);
    *(unsigned*)(sm + ql*132 + d0*2)        = w0;
    *(unsigned*)(sm + ql*132 + (32 + d0)*2) = w1;
  }
  __syncthreads();
  {
    const int rw = t >> 1, hf = t & 1;
    const int b = bh >> 4, h = bh & 15;
    unsigned short* dst = og + ((size_t)b*2048 + q0 + rw)*1024 + h*64 + hf*32;
#pragma unroll
    for (int u = 0; u < 8; u++){
      short4 v4 = *(short4*)(sm + rw*132 + hf*64 + u*8);
      *(short4*)(dst + u*4) = v4;
    }
  }
}

// ---------------------------------------------------------------- launcher
extern "C" void kernel_launch(void* const* d_in, const int* in_sizes, int n_in,
                              void* d_out, int out_size, void* d_ws, size_t ws_size,
                              hipStream_t stream)
{
  const float* x      = (const float*)d_in[0];
  const float* qkv_w  = (const float*)d_in[1];
  const float* qn_w   = (const float*)d_in[2];
  const float* qn_b   = (const float*)d_in[3];
  const float* kn_w   = (const float*)d_in[4];
  const float* kn_b   = (const float*)d_in[5];
  const float* proj_w = (const float*)d_in[6];
  const float* proj_b = (const float*)d_in[7];
  float* out = (float*)d_out;

  unsigned short* x16   = (unsigned short*)d_ws;          // 4096*1024
  unsigned short* w1    = x16   + (size_t)4096*1024;      // 3072*1024
  unsigned short* w2    = w1    + (size_t)3072*1024;      // 1024*1024
  unsigned short* qkv16 = w2    + (size_t)1024*1024;      // 4096*3072
  unsigned short* q16   = qkv16 + (size_t)4096*3072;      // 2*16*2048*64
  unsigned short* k16   = q16   + (size_t)4194304;
  unsigned short* vt16  = k16   + (size_t)4194304;
  unsigned short* o16   = qkv16;                          // alias: qkv dead after lnrope
  float* ct = (float*)x16;                                // alias: x16 dead after QKV gemm
  float* st = ct + 32768;

  cast3_kernel<<<8192, 256, 0, stream>>>(x, qkv_w, proj_w, x16, w1, w2);
  gemm_bt<0><<<dim3(24, 32), 256, 0, stream>>>(x16, w1, qkv16, nullptr, nullptr, 4096, 3072, 1024);
  rope_table<<<128, 256, 0, stream>>>(ct, st);
  lnrope_kernel<<<1024, 256, 0, stream>>>(qkv16, qn_w, qn_b, kn_w, kn_b, ct, st, q16, k16, vt16);
  attn_kernel<<<512, 256, 0, stream>>>(q16, k16, vt16, o16);
  gemm_bt<1><<<dim3(8, 32), 256, 0, stream>>>(o16, w2, nullptr, out, proj_b, 4096, 1024, 1024);
}